// Round 18
// baseline (132.587 us; speedup 1.0000x reference)
//
#include <hip/hip_runtime.h>
#include <hip/hip_fp16.h>
#include <math.h>

typedef __attribute__((ext_vector_type(8))) _Float16 half8;
typedef __attribute__((ext_vector_type(4))) _Float16 half4;
typedef __attribute__((ext_vector_type(4))) float f32x4;
typedef __attribute__((ext_vector_type(16))) float f32x16;
typedef __attribute__((ext_vector_type(4))) unsigned uint4v;

#define HQ 16
#define HK 4
#define DH 64
#define NB 2
#define SEQ 2048
#define EDIM 1024
#define KD 1024

// direct global->LDS 16B async copy; LDS dest = wave-uniform base + lane*16
__device__ __forceinline__ void gload16(const void* g, void* l) {
  __builtin_amdgcn_global_load_lds(
      (const __attribute__((address_space(1))) void*)g,
      (__attribute__((address_space(3))) void*)l, 16, 0, 0);
}

// ---------------- prep (fused): x->f16, RoPE table, 4x W transpose ----------------
// blocks 0..4095: cvt x; 4096..4607: rope table; 4608..5631: transpose_w (z=zz>>8)
__global__ __launch_bounds__(256) void prep_all(
    const float* __restrict__ x, _Float16* __restrict__ xh,
    const int* __restrict__ qpos, float2* __restrict__ tab,
    const float* __restrict__ Wq, const float* __restrict__ Wk,
    const float* __restrict__ Wv, const float* __restrict__ Wo,
    _Float16* __restrict__ WT, _Float16* __restrict__ WoT) {
  __shared__ float t[64][65];
  int bx = blockIdx.x;
  int tid = threadIdx.x;
  if (bx < 4096) {
    int i = bx * 256 + tid;
    float4 v = ((const float4*)x)[i];
    half4 h;
    h[0] = (_Float16)v.x; h[1] = (_Float16)v.y; h[2] = (_Float16)v.z; h[3] = (_Float16)v.w;
    *(half4*)(xh + (size_t)i * 4) = h;
    return;
  }
  if (bx < 4608) {
    int i = (bx - 4096) * 256 + tid;     // 0 .. 4096*32-1
    int row = i >> 5, d = i & 31;
    float ang = (float)qpos[row] * expf((float)d * -0.2878231366242558f); // -ln(1e4)/32
    float sn, cs;
    sincosf(ang, &sn, &cs);
    tab[i] = make_float2(sn, cs);
    return;
  }
  int zz = bx - 4608;                    // 0..1023
  int z = zz >> 8, rem = zz & 255;
  int bxx = rem & 15, by = rem >> 4;
  const float* W;
  _Float16* dst;
  int N, roff;
  if (z == 0)      { W = Wq; N = 1024; roff = 0;    dst = WT; }
  else if (z == 1) { W = Wk; N = 256;  roff = 1024; dst = WT;  if (bxx >= 4) return; }
  else if (z == 2) { W = Wv; N = 256;  roff = 1280; dst = WT;  if (bxx >= 4) return; }
  else             { W = Wo; N = 1024; roff = 0;    dst = WoT; }

  int n0 = bxx * 64, k0 = by * 64;
#pragma unroll
  for (int p = 0; p < 4; ++p) {
    int idx = tid + p * 256;
    int r = idx >> 4;      // k row 0..63
    int c4 = idx & 15;     // float4 col
    float4 v = *(const float4*)(W + (size_t)(k0 + r) * N + n0 + c4 * 4);
    t[r][c4 * 4 + 0] = v.x; t[r][c4 * 4 + 1] = v.y;
    t[r][c4 * 4 + 2] = v.z; t[r][c4 * 4 + 3] = v.w;
  }
  __syncthreads();
#pragma unroll
  for (int p = 0; p < 4; ++p) {
    int idx = tid + p * 256;
    int n = idx >> 4;
    int k4 = idx & 15;
    half4 h;
    h[0] = (_Float16)t[k4 * 4 + 0][n]; h[1] = (_Float16)t[k4 * 4 + 1][n];
    h[2] = (_Float16)t[k4 * 4 + 2][n]; h[3] = (_Float16)t[k4 * 4 + 3][n];
    *(half4*)(dst + (size_t)(roff + n0 + n) * KD + k0 + k4 * 4) = h;
  }
}

// ---------------- prep: V [bh][s][d] -> V^T [bh][d][s] ----------------
__global__ __launch_bounds__(256) void transpose_v_kernel(const _Float16* __restrict__ vhp,
                                                          _Float16* __restrict__ vtp) {
  __shared__ _Float16 t[64][72];
  int bh = blockIdx.y;           // 0..7  (b*HK+hk)
  int s0 = blockIdx.x * 64;      // 32 tiles over SEQ
  const _Float16* src = vhp + ((size_t)bh * SEQ + s0) * DH;
  _Float16* dst = vtp + (size_t)bh * DH * SEQ + s0;
  int tid = threadIdx.x;
#pragma unroll
  for (int p = 0; p < 2; ++p) {
    int idx = tid + p * 256;     // 512 half8s
    int r = idx >> 3, c8 = idx & 7;
    half8 v = *(const half8*)(src + (size_t)r * DH + c8 * 8);
#pragma unroll
    for (int i = 0; i < 8; ++i) t[r][c8 * 8 + i] = v[i];
  }
  __syncthreads();
#pragma unroll
  for (int p = 0; p < 2; ++p) {
    int idx = tid + p * 256;
    int d = idx >> 3, c8 = idx & 7;
    half8 v;
#pragma unroll
    for (int i = 0; i < 8; ++i) v[i] = t[c8 * 8 + i][d];
    *(half8*)(dst + (size_t)d * SEQ + c8 * 8) = v;
  }
}

// swizzle: XOR bits 4-6 of the byte offset with row&7
#define SWZ(r, kb) ((kb) ^ (((r) & 7) << 4))

// ---------------- K1: fused QKV GEMM + RoPE, BM=64 x BN=128, BK=128 ----------------
__global__ __launch_bounds__(256) void gemm_qkv_rope(
    const _Float16* __restrict__ xh, const _Float16* __restrict__ WT,
    const float2* __restrict__ rtab,
    _Float16* __restrict__ qh, _Float16* __restrict__ kh, _Float16* __restrict__ vh) {
  __shared__ char As[64 * 128 * 2];    // 16KB [m][k] swz, row 256B
  __shared__ char Bs[128 * 128 * 2];   // 32KB [n][k] swz, row 256B
  int tid = threadIdx.x, lane = tid & 63, wid = tid >> 6;
  int wr = wid >> 1, wc = wid & 1;
  int bm = blockIdx.x, bn = blockIdx.y;

  const char* Ag = (const char*)(xh + (size_t)bm * 64 * KD);
  const char* Bg = (const char*)(WT + (size_t)bn * 128 * KD);

  int rSl = lane >> 4;                 // row-in-slot 0..3
  int cS = (lane & 15) * 16;           // byte col within 256B row

  f32x4 acc[2][4] = {};

  for (int kt = 0; kt < KD / 128; ++kt) {
#pragma unroll
    for (int p = 0; p < 4; ++p) {                  // A: 16 slots over 4 waves
      int sa = wid * 4 + p;
      int r = sa * 4 + rSl;
      gload16(Ag + (size_t)r * (KD * 2) + kt * 256 + (cS ^ ((r & 7) << 4)),
              As + sa * 1024);
    }
#pragma unroll
    for (int p = 0; p < 8; ++p) {                  // B: 32 slots over 4 waves
      int sb = wid * 8 + p;
      int r = sb * 4 + rSl;
      gload16(Bg + (size_t)r * (KD * 2) + kt * 256 + (cS ^ ((r & 7) << 4)),
              Bs + sb * 1024);
    }
    __syncthreads();
#pragma unroll
    for (int kk = 0; kk < 4; ++kk) {
      int kb = kk * 64 + (lane >> 4) * 16;
      half8 af[2], bf[4];
#pragma unroll
      for (int mf = 0; mf < 2; ++mf) {
        int r = wr * 32 + mf * 16 + (lane & 15);
        af[mf] = *(const half8*)(As + r * 256 + SWZ(r, kb));
      }
#pragma unroll
      for (int nf = 0; nf < 4; ++nf) {
        int r = wc * 64 + nf * 16 + (lane & 15);
        bf[nf] = *(const half8*)(Bs + r * 256 + SWZ(r, kb));
      }
#pragma unroll
      for (int mf = 0; mf < 2; ++mf)
#pragma unroll
        for (int nf = 0; nf < 4; ++nf)
          acc[mf][nf] = __builtin_amdgcn_mfma_f32_16x16x32_f16(af[mf], bf[nf], acc[mf][nf], 0, 0, 0);
    }
    __syncthreads();
  }

  // epilogue: wave covers 64 contiguous cols = exactly one head
  int col0 = bn * 128 + wc * 64;
  int row_base = bm * 64 + wr * 32;
#pragma unroll
  for (int mf = 0; mf < 2; ++mf) {
#pragma unroll
    for (int j = 0; j < 4; ++j) {
      int row = row_base + mf * 16 + (lane >> 4) * 4 + j;
      int b = row >> 11, s = row & (SEQ - 1);
      if (col0 < 1024) {
        int hq = col0 >> 6;
        size_t base = (((size_t)b * HQ + hq) * SEQ + s) * DH;
#pragma unroll
        for (int nf = 0; nf < 2; ++nf) {
          int d = nf * 16 + (lane & 15);  // 0..31
          float2 scv = rtab[row * 32 + d];
          float x1 = acc[mf][nf][j], x2 = acc[mf][nf + 2][j];
          qh[base + d]      = (_Float16)(x1 * scv.y - x2 * scv.x);
          qh[base + d + 32] = (_Float16)(x2 * scv.y + x1 * scv.x);
        }
      } else if (col0 < 1280) {
        int hk = (col0 - 1024) >> 6;
        size_t base = (((size_t)b * HK + hk) * SEQ + s) * DH;
#pragma unroll
        for (int nf = 0; nf < 2; ++nf) {
          int d = nf * 16 + (lane & 15);
          float2 scv = rtab[row * 32 + d];
          float x1 = acc[mf][nf][j], x2 = acc[mf][nf + 2][j];
          kh[base + d]      = (_Float16)(x1 * scv.y - x2 * scv.x);
          kh[base + d + 32] = (_Float16)(x2 * scv.y + x1 * scv.x);
        }
      } else {
        int hk = (col0 - 1280) >> 6;
        size_t base = (((size_t)b * HK + hk) * SEQ + s) * DH;
#pragma unroll
        for (int nf = 0; nf < 4; ++nf) {
          int d = nf * 16 + (lane & 15);
          vh[base + d] = (_Float16)acc[mf][nf][j];
        }
      }
    }
  }
}

// ---------------- K2: flash attention (R15 body + isolated defer-max T13) ----------------
// grid: (qt=16, bh=32). block 256 = 4 waves x 32 q-rows. KV tile = 128.
// Single-buffer 32KB LDS + __syncthreads (full drain) at both sync points.
// defer-max THR=8 (log2 domain): P bounded by 2^8; rescale skipped when
// __any(pm > m+8) is false. Deterministic (wave-uniform branch). R12-proven
// on this same sync structure (passed + revalidated).
__global__ __launch_bounds__(256) void attn_kernel(
    const _Float16* __restrict__ qh, const _Float16* __restrict__ kh,
    const _Float16* __restrict__ vt, _Float16* __restrict__ oh) {
  __shared__ char Ks[128 * 64 * 2];      // 16KB [kv][d] swz, row 128B
  __shared__ char Vs[64 * 128 * 2];      // 16KB [d][kv] swz, row 256B

  int tid = threadIdx.x, lane = tid & 63, wid = tid >> 6;
  int half = lane >> 5, l31 = lane & 31;
  bool lopart = (half == 0);
  int qt = blockIdx.x, bh = blockIdx.y;
  int b = bh >> 4, hq = bh & 15, hk = hq >> 2;

  const _Float16* Qg = qh + (((size_t)b * HQ + hq) * SEQ + qt * 128 + wid * 32 + l31) * DH;
  const char* Kg = (const char*)(kh + (((size_t)b * HK + hk) * SEQ) * DH);
  const char* Vtg = (const char*)(vt + (size_t)(b * HK + hk) * DH * SEQ);

  // Q as B-fragments: lane holds Q[q=l31][d = ks*16 + half*8 + i], pre-scaled
  const _Float16 l2e = (_Float16)1.44269504f;
  half8 qf[4];
#pragma unroll
  for (int ks = 0; ks < 4; ++ks) {
    half8 q0 = *(const half8*)(Qg + ks * 16 + half * 8);
#pragma unroll
    for (int i = 0; i < 8; ++i) q0[i] = q0[i] * l2e;
    qf[ks] = q0;
  }

  // staging source addressing (pre-swizzled so linear LDS dest = swz layout)
  int colK = 16 * ((lane & 7) ^ (lane >> 3));
  int rK = lane >> 3;

  f32x16 oacc[2] = {};   // O^T: lane q=l31, d=dblk*32+(r&3)+8*(r>>2)+4*half
  float m = -3e38f, l = 0.f;

  for (int kt = 0; kt < SEQ / 128; ++kt) {
    // stage K [128 kv][64 d] and V^T [64 d][128 kv]: 8 gload16 per thread
#pragma unroll
    for (int p = 0; p < 4; ++p) {
      int r = (wid * 4 + p) * 8 + rK;
      gload16(Kg + (size_t)(kt * 128 + r) * 128 + colK, Ks + (wid * 4 + p) * 1024);
      int d = (wid * 4 + p) * 4 + (lane >> 4);
      int colV = ((lane & 15) * 16) ^ ((d & 7) << 4);
      gload16(Vtg + (size_t)d * (SEQ * 2) + kt * 256 + colV, Vs + (wid * 4 + p) * 1024);
    }
    __syncthreads();    // full vmcnt drain: LDS tile ready for all waves

    // S^T = K Q^T : 4 kv-blocks of 32, K-dim d=64 in 4 slices of 16
    f32x16 sacc[4] = {};
    __builtin_amdgcn_s_setprio(1);
#pragma unroll
    for (int b4 = 0; b4 < 4; ++b4) {
      int r = b4 * 32 + l31;
#pragma unroll
      for (int ks = 0; ks < 4; ++ks) {
        half8 kf = *(const half8*)(Ks + r * 128 + SWZ(r, ks * 32 + half * 16));
        sacc[b4] = __builtin_amdgcn_mfma_f32_32x32x16_f16(kf, qf[ks], sacc[b4], 0, 0, 0);
      }
    }
    __builtin_amdgcn_s_setprio(0);

    // row max: pairwise tree (depth 6), then cross-half combine
    float pmb[4];
#pragma unroll
    for (int b4 = 0; b4 < 4; ++b4) {
      f32x16 v = sacc[b4];
      float a0 = fmaxf(v[0], v[1]),   a1 = fmaxf(v[2], v[3]);
      float a2 = fmaxf(v[4], v[5]),   a3 = fmaxf(v[6], v[7]);
      float a4 = fmaxf(v[8], v[9]),   a5 = fmaxf(v[10], v[11]);
      float a6 = fmaxf(v[12], v[13]), a7 = fmaxf(v[14], v[15]);
      float b0 = fmaxf(a0, a1), b1 = fmaxf(a2, a3);
      float b2 = fmaxf(a4, a5), b3 = fmaxf(a6, a7);
      pmb[b4] = fmaxf(fmaxf(b0, b1), fmaxf(b2, b3));
    }
    float pm = fmaxf(fmaxf(pmb[0], pmb[1]), fmaxf(pmb[2], pmb[3]));
    pm = fmaxf(pm, __shfl_xor(pm, 32, 64));
    if (__any(pm > m + 8.f)) {     // defer-max (T13): P bounded by 2^8
      float mnew = fmaxf(m, pm);
      float alpha = __builtin_amdgcn_exp2f(m - mnew);
      m = mnew;
      oacc[0] *= alpha;
      oacc[1] *= alpha;
      l *= alpha;
    }
    float ps0 = 0.f, ps1 = 0.f, ps2 = 0.f, ps3 = 0.f;

    // per kv-block: exp, pack, build PV B-frags in-register, PV MFMA
#pragma unroll
    for (int b4 = 0; b4 < 4; ++b4) {
      float e[16];
#pragma unroll
      for (int r = 0; r < 4; ++r)  { e[r] = __builtin_amdgcn_exp2f(sacc[b4][r] - m);  ps0 += e[r]; }
#pragma unroll
      for (int r = 4; r < 8; ++r)  { e[r] = __builtin_amdgcn_exp2f(sacc[b4][r] - m);  ps1 += e[r]; }
#pragma unroll
      for (int r = 8; r < 12; ++r) { e[r] = __builtin_amdgcn_exp2f(sacc[b4][r] - m);  ps2 += e[r]; }
#pragma unroll
      for (int r = 12; r < 16; ++r){ e[r] = __builtin_amdgcn_exp2f(sacc[b4][r] - m);  ps3 += e[r]; }
      unsigned W0[4], W1[4];
#pragma unroll
      for (int qd = 0; qd < 4; ++qd) {
        W0[qd] = __builtin_bit_cast(unsigned, __builtin_amdgcn_cvt_pkrtz(e[4 * qd + 0], e[4 * qd + 1]));
        W1[qd] = __builtin_bit_cast(unsigned, __builtin_amdgcn_cvt_pkrtz(e[4 * qd + 2], e[4 * qd + 3]));
      }
      half8 pf[2];
#pragma unroll
      for (int s = 0; s < 2; ++s) {
        unsigned selA = lopart ? W0[2 * s + 1] : W0[2 * s];
        unsigned crA = (unsigned)__shfl_xor((int)selA, 32, 64);
        unsigned selB = lopart ? W1[2 * s + 1] : W1[2 * s];
        unsigned crB = (unsigned)__shfl_xor((int)selB, 32, 64);
        uint4v u;
        u[0] = lopart ? W0[2 * s] : crA;
        u[1] = lopart ? W1[2 * s] : crB;
        u[2] = lopart ? crA : W0[2 * s + 1];
        u[3] = lopart ? crB : W1[2 * s + 1];
        pf[s] = __builtin_bit_cast(half8, u);
      }
      __builtin_amdgcn_s_setprio(1);
#pragma unroll
      for (int s = 0; s < 2; ++s) {
        int kvb = b4 * 64 + s * 32 + half * 16;
#pragma unroll
        for (int dblk = 0; dblk < 2; ++dblk) {
          int d = dblk * 32 + l31;
          half8 vf = *(const half8*)(Vs + d * 256 + SWZ(d, kvb));
          oacc[dblk] = __builtin_amdgcn_mfma_f32_32x32x16_f16(vf, pf[s], oacc[dblk], 0, 0, 0);
        }
      }
      __builtin_amdgcn_s_setprio(0);
    }
    float ps = (ps0 + ps1) + (ps2 + ps3);
    ps += __shfl_xor(ps, 32, 64);
    l += ps;
    __syncthreads();    // all reads done before next tile overwrites LDS
  }

  // normalize + write [B][S][HQ*DH]; lane owns q = l31, 32 d-values per dblk
  int s = qt * 128 + wid * 32 + l31;
  float invl = 1.f / l;
  size_t base = ((size_t)b * SEQ + s) * 1024 + hq * 64;
#pragma unroll
  for (int dblk = 0; dblk < 2; ++dblk) {
#pragma unroll
    for (int qd = 0; qd < 4; ++qd) {
      half4 o;
#pragma unroll
      for (int j = 0; j < 4; ++j) o[j] = (_Float16)(oacc[dblk][qd * 4 + j] * invl);
      *(half4*)(oh + base + dblk * 32 + qd * 8 + half * 4) = o;
    }
  }
}

// ---------------- K3: output projection, BM=64 x BN=128, BK=128, fp32 out ----------------
__global__ __launch_bounds__(256) void gemm_out(
    const _Float16* __restrict__ ah, const _Float16* __restrict__ WoT,
    float* __restrict__ out) {
  __shared__ char As[64 * 128 * 2];    // 16KB
  __shared__ char Bs[128 * 128 * 2];   // 32KB
  int tid = threadIdx.x, lane = tid & 63, wid = tid >> 6;
  int wr = wid >> 1, wc = wid & 1;
  int bm = blockIdx.x, bn = blockIdx.y;
  const char* Ag = (const char*)(ah + (size_t)bm * 64 * KD);
  const char* Bg = (const char*)(WoT + (size_t)bn * 128 * KD);
  int rSl = lane >> 4;
  int cS = (lane & 15) * 16;
  f32x4 acc[2][4] = {};

  for (int kt = 0; kt < KD / 128; ++kt) {
#pragma unroll
    for (int p = 0; p < 4; ++p) {
      int sa = wid * 4 + p;
      int r = sa * 4 + rSl;
      gload16(Ag + (size_t)r * (KD * 2) + kt * 256 + (cS ^ ((r & 7) << 4)),
              As + sa * 1024);
    }
#pragma unroll
    for (int p = 0; p < 8; ++p) {
      int sb = wid * 8 + p;
      int r = sb * 4 + rSl;
      gload16(Bg + (size_t)r * (KD * 2) + kt * 256 + (cS ^ ((r & 7) << 4)),
              Bs + sb * 1024);
    }
    __syncthreads();
#pragma unroll
    for (int kk = 0; kk < 4; ++kk) {
      int kb = kk * 64 + (lane >> 4) * 16;
      half8 af[2], bf[4];
#pragma unroll
      for (int mf = 0; mf < 2; ++mf) {
        int r = wr * 32 + mf * 16 + (lane & 15);
        af[mf] = *(const half8*)(As + r * 256 + SWZ(r, kb));
      }
#pragma unroll
      for (int nf = 0; nf < 4; ++nf) {
        int r = wc * 64 + nf * 16 + (lane & 15);
        bf[nf] = *(const half8*)(Bs + r * 256 + SWZ(r, kb));
      }
#pragma unroll
      for (int mf = 0; mf < 2; ++mf)
#pragma unroll
        for (int nf = 0; nf < 4; ++nf)
          acc[mf][nf] = __builtin_amdgcn_mfma_f32_16x16x32_f16(af[mf], bf[nf], acc[mf][nf], 0, 0, 0);
    }
    __syncthreads();
  }

  int row0 = bm * 64 + wr * 32, col0 = bn * 128 + wc * 64;
#pragma unroll
  for (int mf = 0; mf < 2; ++mf)
#pragma unroll
    for (int j = 0; j < 4; ++j) {
      int row = row0 + mf * 16 + (lane >> 4) * 4 + j;
#pragma unroll
      for (int nf = 0; nf < 4; ++nf)
        out[(size_t)row * 1024 + col0 + nf * 16 + (lane & 15)] = acc[mf][nf][j];
    }
}

// ---------------- launch ----------------
extern "C" void kernel_launch(void* const* d_in, const int* in_sizes, int n_in,
                              void* d_out, int out_size, void* d_ws, size_t ws_size,
                              hipStream_t stream) {
  const float* x  = (const float*)d_in[0];
  const int* qpos = (const int*)d_in[1];
  const float* Wq = (const float*)d_in[2];
  const float* Wk = (const float*)d_in[3];
  const float* Wv = (const float*)d_in[4];
  const float* Wo = (const float*)d_in[5];
  float* out = (float*)d_out;

  char* ws = (char*)d_ws;
  _Float16* xh  = (_Float16*)(ws);                 // 8 MB  [4096][1024]
  _Float16* WT  = (_Float16*)(ws + 8388608);       // 3 MB  [1536][1024] (q,k,v stacked)
  _Float16* WoT = (_Float16*)(ws + 11534336);      // 2 MB  [1024][1024]
  _Float16* qhp = (_Float16*)(ws + 13631488);      // 8 MB  [B][HQ][S][D]
  _Float16* khp = (_Float16*)(ws + 22020096);      // 2 MB  [B][HK][S][D]
  _Float16* vhp = (_Float16*)(ws + 24117248);      // 2 MB  [B][HK][S][D]
  _Float16* ohp = (_Float16*)(ws + 26214400);      // 8 MB  [4096][1024]
  float2*   rtab = (float2*)(ws + 34603008);       // 1 MB  [4096][32]
  _Float16* vtp = (_Float16*)(ws + 35651584);      // 2 MB  [B][HK][D][S]

  prep_all<<<5632, 256, 0, stream>>>(x, xh, qpos, rtab, Wq, Wk, Wv, Wo, WT, WoT);
  gemm_qkv_rope<<<dim3(64, 12), 256, 0, stream>>>(xh, WT, rtab, qhp, khp, vhp);
  transpose_v_kernel<<<dim3(32, 8), 256, 0, stream>>>(vhp, vtp);
  attn_kernel<<<dim3(16, 32), 256, 0, stream>>>(qhp, khp, vtp, ohp);
  gemm_out<<<dim3(64, 8), 256, 0, stream>>>(ohp, WoT, out);
}

// Round 19
// 108.932 us; speedup vs baseline: 1.2172x; 1.2172x over previous
//
#include <hip/hip_runtime.h>
#include <hip/hip_fp16.h>
#include <math.h>

typedef __attribute__((ext_vector_type(8))) _Float16 half8;
typedef __attribute__((ext_vector_type(4))) _Float16 half4;
typedef __attribute__((ext_vector_type(4))) float f32x4;
typedef __attribute__((ext_vector_type(16))) float f32x16;
typedef __attribute__((ext_vector_type(4))) unsigned uint4v;

#define HQ 16
#define HK 4
#define DH 64
#define NB 2
#define SEQ 2048
#define EDIM 1024
#define KD 1024

// direct global->LDS 16B async copy; LDS dest = wave-uniform base + lane*16
__device__ __forceinline__ void gload16(const void* g, void* l) {
  __builtin_amdgcn_global_load_lds(
      (const __attribute__((address_space(1))) void*)g,
      (__attribute__((address_space(3))) void*)l, 16, 0, 0);
}

// ---------------- prep (fused): x->f16, RoPE table, 4x W transpose ----------------
// blocks 0..4095: cvt x; 4096..4607: rope table; 4608..5631: transpose_w (z=zz>>8)
__global__ __launch_bounds__(256) void prep_all(
    const float* __restrict__ x, _Float16* __restrict__ xh,
    const int* __restrict__ qpos, float2* __restrict__ tab,
    const float* __restrict__ Wq, const float* __restrict__ Wk,
    const float* __restrict__ Wv, const float* __restrict__ Wo,
    _Float16* __restrict__ WT, _Float16* __restrict__ WoT) {
  __shared__ float t[64][65];
  int bx = blockIdx.x;
  int tid = threadIdx.x;
  if (bx < 4096) {
    int i = bx * 256 + tid;
    float4 v = ((const float4*)x)[i];
    half4 h;
    h[0] = (_Float16)v.x; h[1] = (_Float16)v.y; h[2] = (_Float16)v.z; h[3] = (_Float16)v.w;
    *(half4*)(xh + (size_t)i * 4) = h;
    return;
  }
  if (bx < 4608) {
    int i = (bx - 4096) * 256 + tid;     // 0 .. 4096*32-1
    int row = i >> 5, d = i & 31;
    float ang = (float)qpos[row] * expf((float)d * -0.2878231366242558f); // -ln(1e4)/32
    float sn, cs;
    sincosf(ang, &sn, &cs);
    tab[i] = make_float2(sn, cs);
    return;
  }
  int zz = bx - 4608;                    // 0..1023
  int z = zz >> 8, rem = zz & 255;
  int bxx = rem & 15, by = rem >> 4;
  const float* W;
  _Float16* dst;
  int N, roff;
  if (z == 0)      { W = Wq; N = 1024; roff = 0;    dst = WT; }
  else if (z == 1) { W = Wk; N = 256;  roff = 1024; dst = WT;  if (bxx >= 4) return; }
  else if (z == 2) { W = Wv; N = 256;  roff = 1280; dst = WT;  if (bxx >= 4) return; }
  else             { W = Wo; N = 1024; roff = 0;    dst = WoT; }

  int n0 = bxx * 64, k0 = by * 64;
#pragma unroll
  for (int p = 0; p < 4; ++p) {
    int idx = tid + p * 256;
    int r = idx >> 4;      // k row 0..63
    int c4 = idx & 15;     // float4 col
    float4 v = *(const float4*)(W + (size_t)(k0 + r) * N + n0 + c4 * 4);
    t[r][c4 * 4 + 0] = v.x; t[r][c4 * 4 + 1] = v.y;
    t[r][c4 * 4 + 2] = v.z; t[r][c4 * 4 + 3] = v.w;
  }
  __syncthreads();
#pragma unroll
  for (int p = 0; p < 4; ++p) {
    int idx = tid + p * 256;
    int n = idx >> 4;
    int k4 = idx & 15;
    half4 h;
    h[0] = (_Float16)t[k4 * 4 + 0][n]; h[1] = (_Float16)t[k4 * 4 + 1][n];
    h[2] = (_Float16)t[k4 * 4 + 2][n]; h[3] = (_Float16)t[k4 * 4 + 3][n];
    *(half4*)(dst + (size_t)(roff + n0 + n) * KD + k0 + k4 * 4) = h;
  }
}

// ---------------- prep: V [bh][s][d] -> V^T [bh][d][s] ----------------
__global__ __launch_bounds__(256) void transpose_v_kernel(const _Float16* __restrict__ vhp,
                                                          _Float16* __restrict__ vtp) {
  __shared__ _Float16 t[64][72];
  int bh = blockIdx.y;           // 0..7  (b*HK+hk)
  int s0 = blockIdx.x * 64;      // 32 tiles over SEQ
  const _Float16* src = vhp + ((size_t)bh * SEQ + s0) * DH;
  _Float16* dst = vtp + (size_t)bh * DH * SEQ + s0;
  int tid = threadIdx.x;
#pragma unroll
  for (int p = 0; p < 2; ++p) {
    int idx = tid + p * 256;     // 512 half8s
    int r = idx >> 3, c8 = idx & 7;
    half8 v = *(const half8*)(src + (size_t)r * DH + c8 * 8);
#pragma unroll
    for (int i = 0; i < 8; ++i) t[r][c8 * 8 + i] = v[i];
  }
  __syncthreads();
#pragma unroll
  for (int p = 0; p < 2; ++p) {
    int idx = tid + p * 256;
    int d = idx >> 3, c8 = idx & 7;
    half8 v;
#pragma unroll
    for (int i = 0; i < 8; ++i) v[i] = t[c8 * 8 + i][d];
    *(half8*)(dst + (size_t)d * SEQ + c8 * 8) = v;
  }
}

// swizzle: XOR bits 4-6 of the byte offset with row&7
#define SWZ(r, kb) ((kb) ^ (((r) & 7) << 4))

// ---------------- K1: fused QKV GEMM + RoPE, BM=64 x BN=128, BK=128 ----------------
__global__ __launch_bounds__(256) void gemm_qkv_rope(
    const _Float16* __restrict__ xh, const _Float16* __restrict__ WT,
    const float2* __restrict__ rtab,
    _Float16* __restrict__ qh, _Float16* __restrict__ kh, _Float16* __restrict__ vh) {
  __shared__ char As[64 * 128 * 2];    // 16KB [m][k] swz, row 256B
  __shared__ char Bs[128 * 128 * 2];   // 32KB [n][k] swz, row 256B
  int tid = threadIdx.x, lane = tid & 63, wid = tid >> 6;
  int wr = wid >> 1, wc = wid & 1;
  int bm = blockIdx.x, bn = blockIdx.y;

  const char* Ag = (const char*)(xh + (size_t)bm * 64 * KD);
  const char* Bg = (const char*)(WT + (size_t)bn * 128 * KD);

  int rSl = lane >> 4;                 // row-in-slot 0..3
  int cS = (lane & 15) * 16;           // byte col within 256B row

  f32x4 acc[2][4] = {};

  for (int kt = 0; kt < KD / 128; ++kt) {
#pragma unroll
    for (int p = 0; p < 4; ++p) {                  // A: 16 slots over 4 waves
      int sa = wid * 4 + p;
      int r = sa * 4 + rSl;
      gload16(Ag + (size_t)r * (KD * 2) + kt * 256 + (cS ^ ((r & 7) << 4)),
              As + sa * 1024);
    }
#pragma unroll
    for (int p = 0; p < 8; ++p) {                  // B: 32 slots over 4 waves
      int sb = wid * 8 + p;
      int r = sb * 4 + rSl;
      gload16(Bg + (size_t)r * (KD * 2) + kt * 256 + (cS ^ ((r & 7) << 4)),
              Bs + sb * 1024);
    }
    __syncthreads();
#pragma unroll
    for (int kk = 0; kk < 4; ++kk) {
      int kb = kk * 64 + (lane >> 4) * 16;
      half8 af[2], bf[4];
#pragma unroll
      for (int mf = 0; mf < 2; ++mf) {
        int r = wr * 32 + mf * 16 + (lane & 15);
        af[mf] = *(const half8*)(As + r * 256 + SWZ(r, kb));
      }
#pragma unroll
      for (int nf = 0; nf < 4; ++nf) {
        int r = wc * 64 + nf * 16 + (lane & 15);
        bf[nf] = *(const half8*)(Bs + r * 256 + SWZ(r, kb));
      }
#pragma unroll
      for (int mf = 0; mf < 2; ++mf)
#pragma unroll
        for (int nf = 0; nf < 4; ++nf)
          acc[mf][nf] = __builtin_amdgcn_mfma_f32_16x16x32_f16(af[mf], bf[nf], acc[mf][nf], 0, 0, 0);
    }
    __syncthreads();
  }

  // epilogue: wave covers 64 contiguous cols = exactly one head
  int col0 = bn * 128 + wc * 64;
  int row_base = bm * 64 + wr * 32;
#pragma unroll
  for (int mf = 0; mf < 2; ++mf) {
#pragma unroll
    for (int j = 0; j < 4; ++j) {
      int row = row_base + mf * 16 + (lane >> 4) * 4 + j;
      int b = row >> 11, s = row & (SEQ - 1);
      if (col0 < 1024) {
        int hq = col0 >> 6;
        size_t base = (((size_t)b * HQ + hq) * SEQ + s) * DH;
#pragma unroll
        for (int nf = 0; nf < 2; ++nf) {
          int d = nf * 16 + (lane & 15);  // 0..31
          float2 scv = rtab[row * 32 + d];
          float x1 = acc[mf][nf][j], x2 = acc[mf][nf + 2][j];
          qh[base + d]      = (_Float16)(x1 * scv.y - x2 * scv.x);
          qh[base + d + 32] = (_Float16)(x2 * scv.y + x1 * scv.x);
        }
      } else if (col0 < 1280) {
        int hk = (col0 - 1024) >> 6;
        size_t base = (((size_t)b * HK + hk) * SEQ + s) * DH;
#pragma unroll
        for (int nf = 0; nf < 2; ++nf) {
          int d = nf * 16 + (lane & 15);
          float2 scv = rtab[row * 32 + d];
          float x1 = acc[mf][nf][j], x2 = acc[mf][nf + 2][j];
          kh[base + d]      = (_Float16)(x1 * scv.y - x2 * scv.x);
          kh[base + d + 32] = (_Float16)(x2 * scv.y + x1 * scv.x);
        }
      } else {
        int hk = (col0 - 1280) >> 6;
        size_t base = (((size_t)b * HK + hk) * SEQ + s) * DH;
#pragma unroll
        for (int nf = 0; nf < 4; ++nf) {
          int d = nf * 16 + (lane & 15);
          vh[base + d] = (_Float16)acc[mf][nf][j];
        }
      }
    }
  }
}

// ---------------- K2: flash attention (R15/R17 body, proven best) ----------------
// grid: (qt=16, bh=32). block 256 = 4 waves x 32 q-rows. KV tile = 128.
// Single-buffer 32KB LDS + __syncthreads (full drain) at both sync points.
// Tree max-reduce + 4-acc ps sums; unconditional rescale (no defer-max:
// the branch costs 2 waves/CU of residency — R18 post-mortem).
__global__ __launch_bounds__(256) void attn_kernel(
    const _Float16* __restrict__ qh, const _Float16* __restrict__ kh,
    const _Float16* __restrict__ vt, _Float16* __restrict__ oh) {
  __shared__ char Ks[128 * 64 * 2];      // 16KB [kv][d] swz, row 128B
  __shared__ char Vs[64 * 128 * 2];      // 16KB [d][kv] swz, row 256B

  int tid = threadIdx.x, lane = tid & 63, wid = tid >> 6;
  int half = lane >> 5, l31 = lane & 31;
  bool lopart = (half == 0);
  int qt = blockIdx.x, bh = blockIdx.y;
  int b = bh >> 4, hq = bh & 15, hk = hq >> 2;

  const _Float16* Qg = qh + (((size_t)b * HQ + hq) * SEQ + qt * 128 + wid * 32 + l31) * DH;
  const char* Kg = (const char*)(kh + (((size_t)b * HK + hk) * SEQ) * DH);
  const char* Vtg = (const char*)(vt + (size_t)(b * HK + hk) * DH * SEQ);

  // Q as B-fragments: lane holds Q[q=l31][d = ks*16 + half*8 + i], pre-scaled
  const _Float16 l2e = (_Float16)1.44269504f;
  half8 qf[4];
#pragma unroll
  for (int ks = 0; ks < 4; ++ks) {
    half8 q0 = *(const half8*)(Qg + ks * 16 + half * 8);
#pragma unroll
    for (int i = 0; i < 8; ++i) q0[i] = q0[i] * l2e;
    qf[ks] = q0;
  }

  // staging source addressing (pre-swizzled so linear LDS dest = swz layout)
  int colK = 16 * ((lane & 7) ^ (lane >> 3));
  int rK = lane >> 3;

  f32x16 oacc[2] = {};   // O^T: lane q=l31, d=dblk*32+(r&3)+8*(r>>2)+4*half
  float m = -3e38f, l = 0.f;

  for (int kt = 0; kt < SEQ / 128; ++kt) {
    // stage K [128 kv][64 d] and V^T [64 d][128 kv]: 8 gload16 per thread
#pragma unroll
    for (int p = 0; p < 4; ++p) {
      int r = (wid * 4 + p) * 8 + rK;
      gload16(Kg + (size_t)(kt * 128 + r) * 128 + colK, Ks + (wid * 4 + p) * 1024);
      int d = (wid * 4 + p) * 4 + (lane >> 4);
      int colV = ((lane & 15) * 16) ^ ((d & 7) << 4);
      gload16(Vtg + (size_t)d * (SEQ * 2) + kt * 256 + colV, Vs + (wid * 4 + p) * 1024);
    }
    __syncthreads();    // full vmcnt drain: LDS tile ready for all waves

    // S^T = K Q^T : 4 kv-blocks of 32, K-dim d=64 in 4 slices of 16
    f32x16 sacc[4] = {};
    __builtin_amdgcn_s_setprio(1);
#pragma unroll
    for (int b4 = 0; b4 < 4; ++b4) {
      int r = b4 * 32 + l31;
#pragma unroll
      for (int ks = 0; ks < 4; ++ks) {
        half8 kf = *(const half8*)(Ks + r * 128 + SWZ(r, ks * 32 + half * 16));
        sacc[b4] = __builtin_amdgcn_mfma_f32_32x32x16_f16(kf, qf[ks], sacc[b4], 0, 0, 0);
      }
    }
    __builtin_amdgcn_s_setprio(0);

    // row max: pairwise tree (depth 6), then cross-half combine
    float pmb[4];
#pragma unroll
    for (int b4 = 0; b4 < 4; ++b4) {
      f32x16 v = sacc[b4];
      float a0 = fmaxf(v[0], v[1]),   a1 = fmaxf(v[2], v[3]);
      float a2 = fmaxf(v[4], v[5]),   a3 = fmaxf(v[6], v[7]);
      float a4 = fmaxf(v[8], v[9]),   a5 = fmaxf(v[10], v[11]);
      float a6 = fmaxf(v[12], v[13]), a7 = fmaxf(v[14], v[15]);
      float b0 = fmaxf(a0, a1), b1 = fmaxf(a2, a3);
      float b2 = fmaxf(a4, a5), b3 = fmaxf(a6, a7);
      pmb[b4] = fmaxf(fmaxf(b0, b1), fmaxf(b2, b3));
    }
    float pm = fmaxf(fmaxf(pmb[0], pmb[1]), fmaxf(pmb[2], pmb[3]));
    pm = fmaxf(pm, __shfl_xor(pm, 32, 64));
    float mnew = fmaxf(m, pm);
    float alpha = __builtin_amdgcn_exp2f(m - mnew);
    m = mnew;
    oacc[0] *= alpha;
    oacc[1] *= alpha;
    l *= alpha;
    float ps0 = 0.f, ps1 = 0.f, ps2 = 0.f, ps3 = 0.f;

    // per kv-block: exp, pack, build PV B-frags in-register, PV MFMA
#pragma unroll
    for (int b4 = 0; b4 < 4; ++b4) {
      float e[16];
#pragma unroll
      for (int r = 0; r < 4; ++r)  { e[r] = __builtin_amdgcn_exp2f(sacc[b4][r] - m);  ps0 += e[r]; }
#pragma unroll
      for (int r = 4; r < 8; ++r)  { e[r] = __builtin_amdgcn_exp2f(sacc[b4][r] - m);  ps1 += e[r]; }
#pragma unroll
      for (int r = 8; r < 12; ++r) { e[r] = __builtin_amdgcn_exp2f(sacc[b4][r] - m);  ps2 += e[r]; }
#pragma unroll
      for (int r = 12; r < 16; ++r){ e[r] = __builtin_amdgcn_exp2f(sacc[b4][r] - m);  ps3 += e[r]; }
      unsigned W0[4], W1[4];
#pragma unroll
      for (int qd = 0; qd < 4; ++qd) {
        W0[qd] = __builtin_bit_cast(unsigned, __builtin_amdgcn_cvt_pkrtz(e[4 * qd + 0], e[4 * qd + 1]));
        W1[qd] = __builtin_bit_cast(unsigned, __builtin_amdgcn_cvt_pkrtz(e[4 * qd + 2], e[4 * qd + 3]));
      }
      half8 pf[2];
#pragma unroll
      for (int s = 0; s < 2; ++s) {
        unsigned selA = lopart ? W0[2 * s + 1] : W0[2 * s];
        unsigned crA = (unsigned)__shfl_xor((int)selA, 32, 64);
        unsigned selB = lopart ? W1[2 * s + 1] : W1[2 * s];
        unsigned crB = (unsigned)__shfl_xor((int)selB, 32, 64);
        uint4v u;
        u[0] = lopart ? W0[2 * s] : crA;
        u[1] = lopart ? W1[2 * s] : crB;
        u[2] = lopart ? crA : W0[2 * s + 1];
        u[3] = lopart ? crB : W1[2 * s + 1];
        pf[s] = __builtin_bit_cast(half8, u);
      }
      __builtin_amdgcn_s_setprio(1);
#pragma unroll
      for (int s = 0; s < 2; ++s) {
        int kvb = b4 * 64 + s * 32 + half * 16;
#pragma unroll
        for (int dblk = 0; dblk < 2; ++dblk) {
          int d = dblk * 32 + l31;
          half8 vf = *(const half8*)(Vs + d * 256 + SWZ(d, kvb));
          oacc[dblk] = __builtin_amdgcn_mfma_f32_32x32x16_f16(vf, pf[s], oacc[dblk], 0, 0, 0);
        }
      }
      __builtin_amdgcn_s_setprio(0);
    }
    float ps = (ps0 + ps1) + (ps2 + ps3);
    ps += __shfl_xor(ps, 32, 64);
    l += ps;
    __syncthreads();    // all reads done before next tile overwrites LDS
  }

  // normalize + write [B][S][HQ*DH]; lane owns q = l31, 32 d-values per dblk
  int s = qt * 128 + wid * 32 + l31;
  float invl = 1.f / l;
  size_t base = ((size_t)b * SEQ + s) * 1024 + hq * 64;
#pragma unroll
  for (int dblk = 0; dblk < 2; ++dblk) {
#pragma unroll
    for (int qd = 0; qd < 4; ++qd) {
      half4 o;
#pragma unroll
      for (int j = 0; j < 4; ++j) o[j] = (_Float16)(oacc[dblk][qd * 4 + j] * invl);
      *(half4*)(oh + base + dblk * 32 + qd * 8 + half * 4) = o;
    }
  }
}

// ---------------- K3: output projection, BM=64 x BN=128, BK=128, fp32 out ----------------
__global__ __launch_bounds__(256) void gemm_out(
    const _Float16* __restrict__ ah, const _Float16* __restrict__ WoT,
    float* __restrict__ out) {
  __shared__ char As[64 * 128 * 2];    // 16KB
  __shared__ char Bs[128 * 128 * 2];   // 32KB
  int tid = threadIdx.x, lane = tid & 63, wid = tid >> 6;
  int wr = wid >> 1, wc = wid & 1;
  int bm = blockIdx.x, bn = blockIdx.y;
  const char* Ag = (const char*)(ah + (size_t)bm * 64 * KD);
  const char* Bg = (const char*)(WoT + (size_t)bn * 128 * KD);
  int rSl = lane >> 4;
  int cS = (lane & 15) * 16;
  f32x4 acc[2][4] = {};

  for (int kt = 0; kt < KD / 128; ++kt) {
#pragma unroll
    for (int p = 0; p < 4; ++p) {
      int sa = wid * 4 + p;
      int r = sa * 4 + rSl;
      gload16(Ag + (size_t)r * (KD * 2) + kt * 256 + (cS ^ ((r & 7) << 4)),
              As + sa * 1024);
    }
#pragma unroll
    for (int p = 0; p < 8; ++p) {
      int sb = wid * 8 + p;
      int r = sb * 4 + rSl;
      gload16(Bg + (size_t)r * (KD * 2) + kt * 256 + (cS ^ ((r & 7) << 4)),
              Bs + sb * 1024);
    }
    __syncthreads();
#pragma unroll
    for (int kk = 0; kk < 4; ++kk) {
      int kb = kk * 64 + (lane >> 4) * 16;
      half8 af[2], bf[4];
#pragma unroll
      for (int mf = 0; mf < 2; ++mf) {
        int r = wr * 32 + mf * 16 + (lane & 15);
        af[mf] = *(const half8*)(As + r * 256 + SWZ(r, kb));
      }
#pragma unroll
      for (int nf = 0; nf < 4; ++nf) {
        int r = wc * 64 + nf * 16 + (lane & 15);
        bf[nf] = *(const half8*)(Bs + r * 256 + SWZ(r, kb));
      }
#pragma unroll
      for (int mf = 0; mf < 2; ++mf)
#pragma unroll
        for (int nf = 0; nf < 4; ++nf)
          acc[mf][nf] = __builtin_amdgcn_mfma_f32_16x16x32_f16(af[mf], bf[nf], acc[mf][nf], 0, 0, 0);
    }
    __syncthreads();
  }

  int row0 = bm * 64 + wr * 32, col0 = bn * 128 + wc * 64;
#pragma unroll
  for (int mf = 0; mf < 2; ++mf)
#pragma unroll
    for (int j = 0; j < 4; ++j) {
      int row = row0 + mf * 16 + (lane >> 4) * 4 + j;
#pragma unroll
      for (int nf = 0; nf < 4; ++nf)
        out[(size_t)row * 1024 + col0 + nf * 16 + (lane & 15)] = acc[mf][nf][j];
    }
}

// ---------------- launch ----------------
extern "C" void kernel_launch(void* const* d_in, const int* in_sizes, int n_in,
                              void* d_out, int out_size, void* d_ws, size_t ws_size,
                              hipStream_t stream) {
  const float* x  = (const float*)d_in[0];
  const int* qpos = (const int*)d_in[1];
  const float* Wq = (const float*)d_in[2];
  const float* Wk = (const float*)d_in[3];
  const float* Wv = (const float*)d_in[4];
  const float* Wo = (const float*)d_in[5];
  float* out = (float*)d_out;

  char* ws = (char*)d_ws;
  _Float16* xh  = (_Float16*)(ws);                 // 8 MB  [4096][1024]
  _Float16* WT  = (_Float16*)(ws + 8388608);       // 3 MB  [1536][1024] (q,k,v stacked)
  _Float16* WoT = (_Float16*)(ws + 11534336);      // 2 MB  [1024][1024]
  _Float16* qhp = (_Float16*)(ws + 13631488);      // 8 MB  [B][HQ][S][D]
  _Float16* khp = (_Float16*)(ws + 22020096);      // 2 MB  [B][HK][S][D]
  _Float16* vhp = (_Float16*)(ws + 24117248);      // 2 MB  [B][HK][S][D]
  _Float16* ohp = (_Float16*)(ws + 26214400);      // 8 MB  [4096][1024]
  float2*   rtab = (float2*)(ws + 34603008);       // 1 MB  [4096][32]
  _Float16* vtp = (_Float16*)(ws + 35651584);      // 2 MB  [B][HK][D][S]

  prep_all<<<5632, 256, 0, stream>>>(x, xh, qpos, rtab, Wq, Wk, Wv, Wo, WT, WoT);
  gemm_qkv_rope<<<dim3(64, 12), 256, 0, stream>>>(xh, WT, rtab, qhp, khp, vhp);
  transpose_v_kernel<<<dim3(32, 8), 256, 0, stream>>>(vhp, vtp);
  attn_kernel<<<dim3(16, 32), 256, 0, stream>>>(qhp, khp, vtp, ohp);
  gemm_out<<<dim3(64, 8), 256, 0, stream>>>(ohp, WoT, out);
}